// Round 2
// baseline (630.476 us; speedup 1.0000x reference)
//
#include <hip/hip_runtime.h>
#include <math.h>

#define PI_F 3.14159265358979323846f

// Problem: x (8,1,2048,2048) fp32 -> out (8,16,128,128) fp32
// 16x16 patches, D_in=256, D=16, 131072 patches (16384/batch).
// Whole pipeline is affine in the patch vector: out = A @ p + u, then GroupNorm.
// GroupNorm is fused into main_k via a per-batch completion flag (256 blocks
// per batch); no separate finalize pass, out is written exactly once.

// Workspace float offsets
#define WS_AH    0      // A as fp16 [16][256] (2048 dwords)
#define WS_U     2048   // u[16]
#define WS_STATS 2112   // sum[64] @2112, sumsq[64] @2176
#define WS_CTR   2240   // 8 uints: per-batch completion counters
#define WS_FLAG  2272   // 8 uints: per-batch params-ready flags (own 128B line)
#define WS_PAR   2304   // per batch 32 floats: sc[16], sh[16]

using half8   = __attribute__((ext_vector_type(8))) _Float16;
using floatx4 = __attribute__((ext_vector_type(4))) float;

// ---------------------------------------------------------------------------
// prep: block e = output channel (16 blocks, 256 thr).
//   F[e][d] = sum_m cw[e][m] e^{+2pi i d m/16}
//   G[e][k] = sum_d (wr+i wi)[d][k] * F[e][d]
//   A[e][t] = (1/64) Re( sum_k G[e][k] e^{-2pi i k t/256} )  -> fp16 in ws
//   u[e]    = cb[e] + 0.25 Re( sum_d (br+i bi)[d] F[e][d] )
// Also zeroes stats + counters + flags for this iteration.
// ---------------------------------------------------------------------------
__global__ __launch_bounds__(256) void prep(
        const float* __restrict__ wr, const float* __restrict__ wi,
        const float* __restrict__ br, const float* __restrict__ bi,
        const float* __restrict__ cw, const float* __restrict__ cb,
        float* __restrict__ ws) {
    const int e = blockIdx.x;
    const int t = threadIdx.x;
    __shared__ float c16[16], s16[16], Fr[16], Fi[16];
    __shared__ float Gr[256], Gi[256], cosT[256], sinT[256];

    float ang = (2.0f * PI_F / 256.0f) * (float)t;
    cosT[t] = cosf(ang);
    sinT[t] = sinf(ang);
    if (t < 16) {
        float a = (2.0f * PI_F / 16.0f) * (float)t;
        c16[t] = cosf(a);
        s16[t] = sinf(a);
    }
    __syncthreads();

    if (t < 16) {                      // F[d=t]
        float fr = 0.f, fi = 0.f;
        #pragma unroll
        for (int m = 0; m < 16; ++m) {
            float c = cw[e * 16 + m];
            fr += c * c16[(t * m) & 15];
            fi += c * s16[(t * m) & 15];
        }
        Fr[t] = fr;
        Fi[t] = fi;
    }
    __syncthreads();

    {                                   // G[k=t]
        float gr = 0.f, gi = 0.f;
        #pragma unroll
        for (int d = 0; d < 16; ++d) {
            float wrv = wr[d * 256 + t];
            float wiv = wi[d * 256 + t];
            gr += wrv * Fr[d] - wiv * Fi[d];
            gi += wrv * Fi[d] + wiv * Fr[d];
        }
        Gr[t] = gr;
        Gi[t] = gi;
    }
    if (t == 0) {                       // u[e]
        float s = 0.f;
        #pragma unroll
        for (int d = 0; d < 16; ++d) s += br[d] * Fr[d] - bi[d] * Fi[d];
        ws[WS_U + e] = cb[e] + 0.25f * s;
    }
    __syncthreads();

    float acc = 0.f;
    for (int k = 0; k < 256; ++k) {
        int a = (k * t) & 255;
        acc += Gr[k] * cosT[a] + Gi[k] * sinT[a];
    }
    _Float16* Ah = (_Float16*)(ws + WS_AH);
    Ah[e * 256 + t] = (_Float16)(acc * (1.0f / 64.0f));

    // zero stats[128] + ctr[8] + flag[8] (+pad) = floats 2112..2303
    if (e == 0 && t < 192) ws[WS_STATS + t] = 0.f;
}

// ---------------------------------------------------------------------------
// main: MFMA GEMM + fused GroupNorm. Block = 256 thr = 4 waves = 64
// consecutive patches of one batch. A-operand (patch data) global->frag
// direct; B-operand (A fp16) in LDS stride 264. C-fragment layout gives each
// lane 4 consecutive-pw patches of ONE channel. Output held in registers
// until this batch's stats complete (per-batch ctr/flag, agent-scope
// atomics), then written normalized exactly once.
// ---------------------------------------------------------------------------
__global__ __launch_bounds__(256, 2) void main_k(
        const float* __restrict__ x, float* __restrict__ ws,
        float* __restrict__ out,
        const float* __restrict__ gamma, const float* __restrict__ beta) {
    __shared__ _Float16 A_sh[16 * 264];   // [ch][k], stride 264 halfs
    __shared__ float s_sum[8], s_ssq[8];
    const int t = threadIdx.x;

    {   // stage A fp16 into padded LDS: thread t -> ch=t>>4, k0=(t&15)*16
        const uint4* asrc = (const uint4*)(ws + WS_AH);
        uint4 q0 = asrc[t * 2];
        uint4 q1 = asrc[t * 2 + 1];
        _Float16* dp = A_sh + (t >> 4) * 264 + (t & 15) * 16;
        *(uint4*)dp       = q0;
        *(uint4*)(dp + 8) = q1;
    }
    if (t < 8) { s_sum[t] = 0.f; s_ssq[t] = 0.f; }

    const int w    = t >> 6;       // wave -> tile 0..3
    const int lane = t & 63;
    const int m    = lane & 15;    // patch-in-tile for A-frag; channel for C
    const int kg   = lane >> 4;    // k-group 0..3

    const float u = ws[WS_U + m];  // bias for this lane's output channel

    const int P0  = blockIdx.x << 6;   // 64 patches, same b, same ph
    const int b   = P0 >> 14;
    const int pi  = P0 & 16383;
    const int ph  = pi >> 7;
    const int pw0 = pi & 127;          // 0 or 64

    const float* xb = x + ((size_t)b << 22)
                        + (size_t)(ph << 4) * 2048
                        + (size_t)((pw0 + w * 16 + m) << 4);
    __syncthreads();

    floatx4 acc = {0.f, 0.f, 0.f, 0.f};
    const int r_off = (kg >> 1);        // row within 2-row step
    const int c_off = (kg & 1) << 3;    // 0 or 8 floats

    #pragma unroll
    for (int s = 0; s < 8; ++s) {
        const float* px = xb + (size_t)(2 * s + r_off) * 2048 + c_off;
        float4 x0 = *(const float4*)px;
        float4 x1 = *(const float4*)(px + 4);
        half8 a;
        a[0] = (_Float16)x0.x; a[1] = (_Float16)x0.y;
        a[2] = (_Float16)x0.z; a[3] = (_Float16)x0.w;
        a[4] = (_Float16)x1.x; a[5] = (_Float16)x1.y;
        a[6] = (_Float16)x1.z; a[7] = (_Float16)x1.w;
        half8 bf = *(const half8*)&A_sh[m * 264 + s * 32 + kg * 8];
        acc = __builtin_amdgcn_mfma_f32_16x16x32_f16(a, bf, acc, 0, 0, 0);
    }

    // C layout: col(ch)=m, row(patch-in-tile)=kg*4+r (consecutive pw).
    float v0 = acc[0] + u;
    float v1 = acc[1] + u;
    float v2 = acc[2] + u;
    float v3 = acc[3] + u;

    // GN stats: sum over kg (xor 16,32) -> per-channel; xor 1 -> group pair
    float sv = v0 + v1 + v2 + v3;
    float qv = v0 * v0 + v1 * v1 + v2 * v2 + v3 * v3;
    sv += __shfl_xor(sv, 16, 64);  qv += __shfl_xor(qv, 16, 64);
    sv += __shfl_xor(sv, 32, 64);  qv += __shfl_xor(qv, 32, 64);
    sv += __shfl_xor(sv, 1, 64);   qv += __shfl_xor(qv, 1, 64);
    if (kg == 0 && (m & 1) == 0) {
        atomicAdd(&s_sum[m >> 1], sv);
        atomicAdd(&s_ssq[m >> 1], qv);
    }
    __syncthreads();
    if (t < 8) {
        atomicAdd(&ws[WS_STATS + b * 8 + t],      s_sum[t]);
        atomicAdd(&ws[WS_STATS + 64 + b * 8 + t], s_ssq[t]);
    }
    __threadfence();       // stats adds device-visible before ctr increment
    __syncthreads();

    unsigned* ctr  = (unsigned*)(ws + WS_CTR);
    unsigned* flag = (unsigned*)(ws + WS_FLAG);
    float*    par  = ws + WS_PAR + b * 32;

    if (t == 0) {
        unsigned old = atomicAdd(&ctr[b], 1u);
        if (old == 255u) {   // last block of this batch: compute GN params
            const float inv_n = 1.0f / 32768.0f;
            #pragma unroll
            for (int g = 0; g < 8; ++g) {
                float S = __hip_atomic_load(&ws[WS_STATS + b * 8 + g],
                                            __ATOMIC_RELAXED, __HIP_MEMORY_SCOPE_AGENT);
                float Q = __hip_atomic_load(&ws[WS_STATS + 64 + b * 8 + g],
                                            __ATOMIC_RELAXED, __HIP_MEMORY_SCOPE_AGENT);
                float mean = S * inv_n;
                float var  = Q * inv_n - mean * mean;
                float rstd = rsqrtf(var + 1e-5f);
                #pragma unroll
                for (int cc = 0; cc < 2; ++cc) {
                    int c = 2 * g + cc;
                    float sc = rstd * gamma[c];
                    float sh = beta[c] - mean * sc;
                    __hip_atomic_store(&par[c], sc,
                                       __ATOMIC_RELAXED, __HIP_MEMORY_SCOPE_AGENT);
                    __hip_atomic_store(&par[16 + c], sh,
                                       __ATOMIC_RELAXED, __HIP_MEMORY_SCOPE_AGENT);
                }
            }
            __hip_atomic_store(&flag[b], 1u,
                               __ATOMIC_RELEASE, __HIP_MEMORY_SCOPE_AGENT);
        }
        // wait for this batch's params (last block falls through immediately)
        while (__hip_atomic_load(&flag[b], __ATOMIC_ACQUIRE,
                                 __HIP_MEMORY_SCOPE_AGENT) == 0u)
            __builtin_amdgcn_s_sleep(2);
    }
    __syncthreads();

    float sc = __hip_atomic_load(&par[m], __ATOMIC_RELAXED, __HIP_MEMORY_SCOPE_AGENT);
    float sh = __hip_atomic_load(&par[16 + m], __ATOMIC_RELAXED, __HIP_MEMORY_SCOPE_AGENT);

    *(float4*)&out[((size_t)b << 18) + (size_t)m * 16384
                   + (size_t)(ph << 7) + (size_t)(pw0 + w * 16 + kg * 4)]
        = make_float4(v0 * sc + sh, v1 * sc + sh, v2 * sc + sh, v3 * sc + sh);
}

extern "C" void kernel_launch(void* const* d_in, const int* in_sizes, int n_in,
                              void* d_out, int out_size, void* d_ws, size_t ws_size,
                              hipStream_t stream) {
    const float* x  = (const float*)d_in[0];
    const float* wr = (const float*)d_in[1];
    const float* wi = (const float*)d_in[2];
    const float* br = (const float*)d_in[3];
    const float* bi = (const float*)d_in[4];
    const float* cw = (const float*)d_in[5];
    const float* cb = (const float*)d_in[6];
    const float* gm = (const float*)d_in[7];
    const float* bt = (const float*)d_in[8];
    float* out = (float*)d_out;
    float* ws  = (float*)d_ws;

    prep<<<16, 256, 0, stream>>>(wr, wi, br, bi, cw, cb, ws);
    main_k<<<2048, 256, 0, stream>>>(x, ws, out, gm, bt);
}

// Round 3
// 220.232 us; speedup vs baseline: 2.8628x; 2.8628x over previous
//
#include <hip/hip_runtime.h>
#include <math.h>

#define PI_F 3.14159265358979323846f

// Problem: x (8,1,2048,2048) fp32 -> out (8,16,128,128) fp32
// 16x16 patches, D_in=256, D=16, 131072 patches (16384/batch).
// Pipeline is affine in the patch vector: out = A @ p + u, then GroupNorm.
//
// main_k is latency-bound with reg-staged loads (VGPR=32 -> ~2KB/CU in
// flight vs 9.2KB needed). Fix: global_load_lds deep prefetch (16 KB in
// flight per wave, no VGPR cost) + counted vmcnt drain, A in registers.

// Workspace float offsets
#define WS_AH    0      // A as fp16 [16][256] (2048 dwords)
#define WS_U     2048   // u[16]
#define WS_STATS 2112   // sum[64] @2112, sumsq[64] @2176

using half8   = __attribute__((ext_vector_type(8))) _Float16;
using floatx4 = __attribute__((ext_vector_type(4))) float;

__device__ __forceinline__ void gload_lds16(const void* g, void* l) {
    __builtin_amdgcn_global_load_lds(
        (const __attribute__((address_space(1))) uint32_t*)g,
        (__attribute__((address_space(3))) uint32_t*)l,
        16, 0, 0);
}

// ---------------------------------------------------------------------------
// prep: block e = output channel (16 blocks, 256 thr).
//   F[e][d] = sum_m cw[e][m] e^{+2pi i d m/16}
//   G[e][k] = sum_d (wr+i wi)[d][k] * F[e][d]
//   A[e][t] = (1/64) Re( sum_k G[e][k] e^{-2pi i k t/256} )  -> fp16 in ws
//   u[e]    = cb[e] + 0.25 Re( sum_d (br+i bi)[d] F[e][d] )
// ---------------------------------------------------------------------------
__global__ __launch_bounds__(256) void prep(
        const float* __restrict__ wr, const float* __restrict__ wi,
        const float* __restrict__ br, const float* __restrict__ bi,
        const float* __restrict__ cw, const float* __restrict__ cb,
        float* __restrict__ ws) {
    const int e = blockIdx.x;
    const int t = threadIdx.x;
    __shared__ float c16[16], s16[16], Fr[16], Fi[16];
    __shared__ float Gr[256], Gi[256], cosT[256], sinT[256];

    float ang = (2.0f * PI_F / 256.0f) * (float)t;
    cosT[t] = cosf(ang);
    sinT[t] = sinf(ang);
    if (t < 16) {
        float a = (2.0f * PI_F / 16.0f) * (float)t;
        c16[t] = cosf(a);
        s16[t] = sinf(a);
    }
    __syncthreads();

    if (t < 16) {                      // F[d=t]
        float fr = 0.f, fi = 0.f;
        #pragma unroll
        for (int m = 0; m < 16; ++m) {
            float c = cw[e * 16 + m];
            fr += c * c16[(t * m) & 15];
            fi += c * s16[(t * m) & 15];
        }
        Fr[t] = fr;
        Fi[t] = fi;
    }
    __syncthreads();

    {                                   // G[k=t]
        float gr = 0.f, gi = 0.f;
        #pragma unroll
        for (int d = 0; d < 16; ++d) {
            float wrv = wr[d * 256 + t];
            float wiv = wi[d * 256 + t];
            gr += wrv * Fr[d] - wiv * Fi[d];
            gi += wrv * Fi[d] + wiv * Fr[d];
        }
        Gr[t] = gr;
        Gi[t] = gi;
    }
    if (t == 0) {                       // u[e]
        float s = 0.f;
        #pragma unroll
        for (int d = 0; d < 16; ++d) s += br[d] * Fr[d] - bi[d] * Fi[d];
        ws[WS_U + e] = cb[e] + 0.25f * s;
    }
    __syncthreads();

    float acc = 0.f;
    for (int k = 0; k < 256; ++k) {
        int a = (k * t) & 255;
        acc += Gr[k] * cosT[a] + Gi[k] * sinT[a];
    }
    _Float16* Ah = (_Float16*)(ws + WS_AH);
    Ah[e * 256 + t] = (_Float16)(acc * (1.0f / 64.0f));

    if (e == 0 && t < 128) ws[WS_STATS + t] = 0.f;   // zero GN stats
}

// ---------------------------------------------------------------------------
// main: MFMA GEMM. Block = 256 thr = 4 waves = 64 consecutive patches.
// x staged via 16x global_load_lds (16B) per wave -> 16 KB in flight, no
// VGPR cost; drained with counted vmcnt (14-2s), never 0 in the loop.
// Per-lane global source is pre-swizzled so the linear LDS dest (base +
// lane*16) IS the read layout: lane reads its 2x ds_read_b128 at lane*16
// (conflict-free). A fp16 lives in 8x half8 registers (static-indexed);
// no mid-kernel barrier. Stats via shfl tree + per-wave LDS slots.
// ---------------------------------------------------------------------------
__global__ __launch_bounds__(256) void main_k(const float* __restrict__ x,
                                              const float* __restrict__ ws,
                                              float* __restrict__ out,
                                              float* __restrict__ stats) {
    __shared__ float x_sh[4 * 4096];      // 16 KB per wave
    __shared__ float s_sum[4][8], s_ssq[4][8];
    const int t = threadIdx.x;

    const int w    = t >> 6;       // wave -> tile 0..3
    const int lane = t & 63;
    const int m    = lane & 15;    // patch-in-tile for A-frag; channel for C
    const int kg   = lane >> 4;    // k-group 0..3
    const int r_off = (kg >> 1);        // row within 2-row step
    const int c_off = (kg & 1) << 3;    // 0 or 8 floats

    // A fragments: 8 steps x 16B per lane, straight to registers (L2-hot).
    const _Float16* Ah = (const _Float16*)(ws + WS_AH);
    half8 Areg[8];
    #pragma unroll
    for (int s = 0; s < 8; ++s)
        Areg[s] = *(const half8*)(Ah + m * 256 + s * 32 + kg * 8);
    const float u = ws[WS_U + m];  // bias for this lane's output channel

    const int P0  = blockIdx.x << 6;   // 64 patches, same b, same ph
    const int b   = P0 >> 14;
    const int pi  = P0 & 16383;
    const int ph  = pi >> 7;
    const int pw0 = pi & 127;          // 0 or 64

    // this lane's patch top-left
    const float* xb = x + ((size_t)b << 22)
                        + (size_t)(ph << 4) * 2048
                        + (size_t)((pw0 + w * 16 + m) << 4);

    // issue all 16 x-prefetches for this wave (j = 2s+h), dest linear:
    // wave_base + j*1024B + lane*16B;  src = the 16B lane wants for (s,h).
    float* lp = x_sh + w * 4096;       // wave-uniform
    #pragma unroll
    for (int j = 0; j < 16; ++j) {
        const int s = j >> 1, h = j & 1;
        const float* src = xb + (size_t)(2 * s + r_off) * 2048 + c_off + 4 * h;
        gload_lds16(src, lp + j * 256);
    }

    floatx4 acc = {0.f, 0.f, 0.f, 0.f};
    const float* xw = x_sh + w * 4096 + lane * 4;   // this lane's read base

#define WAITVM(N) asm volatile("s_waitcnt vmcnt(" #N ")" ::: "memory")
#define STEP(S, VM) do {                                                 \
        WAITVM(VM);                                                      \
        const float4 c0 = *(const float4*)(xw + (S) * 512);              \
        const float4 c1 = *(const float4*)(xw + (S) * 512 + 256);        \
        half8 a;                                                         \
        a[0] = (_Float16)c0.x; a[1] = (_Float16)c0.y;                    \
        a[2] = (_Float16)c0.z; a[3] = (_Float16)c0.w;                    \
        a[4] = (_Float16)c1.x; a[5] = (_Float16)c1.y;                    \
        a[6] = (_Float16)c1.z; a[7] = (_Float16)c1.w;                    \
        acc = __builtin_amdgcn_mfma_f32_16x16x32_f16(a, Areg[S], acc,    \
                                                     0, 0, 0);           \
    } while (0)

    STEP(0, 14);
    STEP(1, 12);
    STEP(2, 10);
    STEP(3, 8);
    STEP(4, 6);
    STEP(5, 4);
    STEP(6, 2);
    STEP(7, 0);
#undef STEP
#undef WAITVM

    // C layout: col(ch)=m, row(patch-in-tile)=kg*4+r (consecutive pw).
    float v0 = acc[0] + u;
    float v1 = acc[1] + u;
    float v2 = acc[2] + u;
    float v3 = acc[3] + u;
    *(float4*)&out[((size_t)b << 18) + (size_t)m * 16384
                   + (size_t)(ph << 7) + (size_t)(pw0 + w * 16 + kg * 4)]
        = make_float4(v0, v1, v2, v3);

    // GN stats: sum over kg (xor 16,32) -> per-channel; xor 1 -> group pair
    float sv = v0 + v1 + v2 + v3;
    float qv = v0 * v0 + v1 * v1 + v2 * v2 + v3 * v3;
    sv += __shfl_xor(sv, 16, 64);  qv += __shfl_xor(qv, 16, 64);
    sv += __shfl_xor(sv, 32, 64);  qv += __shfl_xor(qv, 32, 64);
    sv += __shfl_xor(sv, 1, 64);   qv += __shfl_xor(qv, 1, 64);
    if (kg == 0 && (m & 1) == 0) {     // one lane per (wave, group) slot
        s_sum[w][m >> 1] = sv;
        s_ssq[w][m >> 1] = qv;
    }
    __syncthreads();
    if (t < 8) {
        float S = s_sum[0][t] + s_sum[1][t] + s_sum[2][t] + s_sum[3][t];
        float Q = s_ssq[0][t] + s_ssq[1][t] + s_ssq[2][t] + s_ssq[3][t];
        atomicAdd(&stats[b * 8 + t],      S);
        atomicAdd(&stats[64 + b * 8 + t], Q);
    }
}

// ---------------------------------------------------------------------------
// finalize: in-place GroupNorm on d_out using accumulated stats.
// ---------------------------------------------------------------------------
__global__ __launch_bounds__(256) void finalize(float* __restrict__ out,
                                                const float* __restrict__ stats,
                                                const float* __restrict__ gamma,
                                                const float* __restrict__ beta) {
    const int i    = blockIdx.x * 256 + threadIdx.x;  // float4 index
    const int flat = i << 2;
    const int b = flat >> 18;
    const int c = (flat >> 14) & 15;
    const int g = c >> 1;

    const float inv_n = 1.0f / 32768.0f;
    float mean = stats[b * 8 + g] * inv_n;
    float var  = stats[64 + b * 8 + g] * inv_n - mean * mean;
    float rstd = rsqrtf(var + 1e-5f);
    float sc = rstd * gamma[c];
    float sh = beta[c] - mean * sc;

    float4 vv = ((float4*)out)[i];
    vv.x = vv.x * sc + sh;
    vv.y = vv.y * sc + sh;
    vv.z = vv.z * sc + sh;
    vv.w = vv.w * sc + sh;
    ((float4*)out)[i] = vv;
}

extern "C" void kernel_launch(void* const* d_in, const int* in_sizes, int n_in,
                              void* d_out, int out_size, void* d_ws, size_t ws_size,
                              hipStream_t stream) {
    const float* x  = (const float*)d_in[0];
    const float* wr = (const float*)d_in[1];
    const float* wi = (const float*)d_in[2];
    const float* br = (const float*)d_in[3];
    const float* bi = (const float*)d_in[4];
    const float* cw = (const float*)d_in[5];
    const float* cb = (const float*)d_in[6];
    const float* gm = (const float*)d_in[7];
    const float* bt = (const float*)d_in[8];
    float* out = (float*)d_out;
    float* ws  = (float*)d_ws;

    prep<<<16, 256, 0, stream>>>(wr, wi, br, bi, cw, cb, ws);
    main_k<<<2048, 256, 0, stream>>>(x, ws, out, ws + WS_STATS);
    finalize<<<2048, 256, 0, stream>>>(out, ws + WS_STATS, gm, bt);
}